// Round 20
// baseline (1135.975 us; speedup 1.0000x reference)
//
#include <hip/hip_runtime.h>
#include <hip/hip_bf16.h>

#define SEQ   110
#define HALFS 55
#define EMB   102
#define HEAD  192

typedef short bf16x8 __attribute__((ext_vector_type(8)));
typedef float f32x4  __attribute__((ext_vector_type(4)));

#define MTS   128               // Mt row stride (shorts)
#define MTROWS 112
#define MT_SHORTS (MTROWS * MTS)   // 14336
#define WES   128               // WvT e-stride

__device__ __forceinline__ short f2bf(float f) {
    unsigned u = __float_as_uint(f);
    unsigned r = u + 0x7fffu + ((u >> 16) & 1u);   // RNE
    return (short)(r >> 16);
}
__device__ __forceinline__ unsigned pk2(float a, float b) {
    return ((unsigned)(unsigned short)f2bf(b) << 16) | (unsigned short)f2bf(a);
}

// ws layout: [ Mt : 112x128 bf16 ][ WvT : 192x128 bf16 ]
// Mt[i][j] = scale * sum_h Wq[j][h] * Wk[i][h]; WvT[h][e] = Wv[e][h]; zero-padded.
__global__ void prep(const float* __restrict__ Wq, const float* __restrict__ Wk,
                     const float* __restrict__ Wv, short* __restrict__ ws) {
    int flat = blockIdx.x * 256 + threadIdx.x;
    if (flat < MT_SHORTS) {
        int i = flat >> 7, j = flat & 127;
        float v = 0.0f;
        if (i < EMB && j < EMB) {
            const float4* q4 = (const float4*)(Wq + j * HEAD);
            const float4* k4 = (const float4*)(Wk + i * HEAD);
            float s = 0.0f;
            #pragma unroll 4
            for (int h4 = 0; h4 < HEAD / 4; ++h4) {
                float4 a = q4[h4], b = k4[h4];
                s += a.x * b.x + a.y * b.y + a.z * b.z + a.w * b.w;
            }
            v = s * 0.07216878364870322f;   // 1/sqrt(192)
        }
        ws[flat] = f2bf(v);
    } else if (flat < MT_SHORTS + HEAD * WES) {
        int idx = flat - MT_SHORTS;
        int h = idx >> 7, e = idx & 127;
        float v = (e < EMB) ? Wv[e * HEAD + h] : 0.0f;
        ws[flat] = f2bf(v);
    }
}

// bf16x8 fragment from a global f32 row at even col e (8B-aligned float2 loads)
__device__ __forceinline__ bf16x8 ldfrag(const float* rowp, int e) {
    const float2* p = (const float2*)(rowp + e);
    float2 a = p[0], b = p[1], c = p[2], d = p[3];
    uint4 q;
    q.x = pk2(a.x, a.y); q.y = pk2(b.x, b.y);
    q.z = pk2(c.x, c.y); q.w = pk2(d.x, d.y);
    bf16x8 rr; __builtin_memcpy(&rr, &q, 16); return rr;
}
// tail frag e=96..103 with e=102,103 zeroed (EMB=102)
__device__ __forceinline__ bf16x8 ldfrag_tail(const float* rowp) {
    const float2* p = (const float2*)(rowp + 96);
    float2 a = p[0], b = p[1], c = p[2];
    uint4 q;
    q.x = pk2(a.x, a.y); q.y = pk2(b.x, b.y);
    q.z = pk2(c.x, c.y); q.w = 0u;
    bf16x8 rr; __builtin_memcpy(&rr, &q, 16); return rr;
}

// ZERO-BARRIER / ZERO-LDS kernel: one wave = one batch, everything in registers,
// x streamed from global (L2) as bf16 frags. 2048 blocks x 256 threads = 8192
// waves, 1 batch each. launch_bounds (256,4) caps VGPR at 128 (16 waves/CU).
// All exchange patterns are the R4-R18 byte-verified shuffles.
__global__ __launch_bounds__(256, 4)
void attn_head(const float* __restrict__ x, const short* __restrict__ ws,
               float* __restrict__ out, int B) {
    const int tid  = threadIdx.x;
    const int w4   = tid >> 6;        // wave in block
    const int lane = tid & 63;
    const int g    = lane >> 4;
    const int r    = lane & 15;

    const short* Mt  = ws;
    const short* WvT = ws + MT_SHORTS;

    bf16x8 zz = {};
    const int src0 = ((g & 1) << 5) + r;
    const int src1 = src0 + 16;
    const bool hi  = (g >> 1) != 0;

    const int p0      = (int)blockIdx.x * 4 + w4;
    const int wstride = (int)gridDim.x * 4;

    #pragma unroll 1
    for (int p = p0; p < B; p += wstride) {
        const float* xb = x + (size_t)p * (SEQ * EMB);
        float* ob = out + (size_t)p * (SEQ * HEAD);

        #pragma unroll 1
        for (int half = 0; half < 2; ++half) {
            const int own = half * HALFS;        // query rows base
            const int oth = HALFS - own;         // key/value rows base

            // ---- phase 1: bp[c] for all 4 query tiles (c unrolled, all-register) ----
            bf16x8 bpA[4], bpB[4];
            #pragma unroll
            for (int c = 0; c < 4; ++c) {
                // bx: own-half query rows s = 16c + r (clamped; rows >=55 unstored)
                bf16x8 bx[4];
                {
                    int rr = 16 * c + r; rr = (rr > 54) ? 54 : rr;
                    const float* rowp = xb + (size_t)(own + rr) * EMB;
                    #pragma unroll
                    for (int kk = 0; kk < 3; ++kk) bx[kk] = ldfrag(rowp, 32 * kk + 8 * g);
                    bx[3] = zz;
                    if (g == 0) bx[3] = ldfrag_tail(rowp);
                }
                // y'^T = Mt @ x_c^T (7 tiles, R18-verified register math)
                unsigned vyp[8][2];
                #pragma unroll
                for (int mt = 0; mt < 7; ++mt) {
                    const short* amp = Mt + (16 * mt + r) * MTS + 8 * g;
                    f32x4 acc = {0.f, 0.f, 0.f, 0.f};
                    #pragma unroll
                    for (int kk = 0; kk < 4; ++kk)
                        acc = __builtin_amdgcn_mfma_f32_16x16x32_bf16(
                            *(const bf16x8*)(amp + 32 * kk), bx[kk], acc, 0, 0, 0);
                    vyp[mt][0] = pk2(acc[0], acc[1]);
                    vyp[mt][1] = pk2(acc[2], acc[3]);
                }
                vyp[7][0] = 0u; vyp[7][1] = 0u;
                // y-exchange -> by[kk] = y'[i=32kk+8g..+7][s=16c+r]
                bf16x8 by[4];
                #pragma unroll
                for (int kk = 0; kk < 4; ++kk) {
                    unsigned e0 = (unsigned)__shfl((int)vyp[2 * kk][0],     src0);
                    unsigned e1 = (unsigned)__shfl((int)vyp[2 * kk][1],     src0);
                    unsigned e2 = (unsigned)__shfl((int)vyp[2 * kk][0],     src1);
                    unsigned e3 = (unsigned)__shfl((int)vyp[2 * kk][1],     src1);
                    unsigned f0 = (unsigned)__shfl((int)vyp[2 * kk + 1][0], src0);
                    unsigned f1 = (unsigned)__shfl((int)vyp[2 * kk + 1][1], src0);
                    unsigned f2 = (unsigned)__shfl((int)vyp[2 * kk + 1][0], src1);
                    unsigned f3 = (unsigned)__shfl((int)vyp[2 * kk + 1][1], src1);
                    uint4 q;
                    q.x = hi ? f0 : e0; q.y = hi ? f1 : e1; q.z = hi ? f2 : e2; q.w = hi ? f3 : e3;
                    __builtin_memcpy(&by[kk], &q, 16);
                }
                // scores: A = key rows t = 16mt + r (streamed from global, clamped)
                float sc[4][4];
                #pragma unroll
                for (int mt = 0; mt < 4; ++mt) {
                    int rr = 16 * mt + r; rr = (rr > 54) ? 54 : rr;
                    const float* rowp = xb + (size_t)(oth + rr) * EMB;
                    bf16x8 axm[4];
                    #pragma unroll
                    for (int kk = 0; kk < 3; ++kk) axm[kk] = ldfrag(rowp, 32 * kk + 8 * g);
                    axm[3] = zz;
                    if (g == 0) axm[3] = ldfrag_tail(rowp);
                    f32x4 acc = {0.f, 0.f, 0.f, 0.f};
                    #pragma unroll
                    for (int kk = 0; kk < 4; ++kk)
                        acc = __builtin_amdgcn_mfma_f32_16x16x32_bf16(axm[kk], by[kk], acc, 0, 0, 0);
                    #pragma unroll
                    for (int j = 0; j < 4; ++j) sc[mt][j] = acc[j];
                }
                #pragma unroll
                for (int j = 0; j < 4; ++j)
                    if (48 + 4 * g + j >= HALFS) sc[3][j] = -1e30f;   // key padding mask

                // softmax over t (16 in-lane + 2 shfl_xor over g-groups)
                float mx = -1e30f;
                #pragma unroll
                for (int mt = 0; mt < 4; ++mt) {
                    #pragma unroll
                    for (int j = 0; j < 4; ++j) mx = fmaxf(mx, sc[mt][j]);
                }
                mx = fmaxf(mx, __shfl_xor(mx, 16));
                mx = fmaxf(mx, __shfl_xor(mx, 32));
                float pr[4][4];
                float sum = 0.f;
                #pragma unroll
                for (int mt = 0; mt < 4; ++mt) {
                    #pragma unroll
                    for (int j = 0; j < 4; ++j) { pr[mt][j] = __expf(sc[mt][j] - mx); sum += pr[mt][j]; }
                }
                sum += __shfl_xor(sum, 16);
                sum += __shfl_xor(sum, 32);
                float rs = 1.0f / sum;

                unsigned pu[4][2];
                #pragma unroll
                for (int mt = 0; mt < 4; ++mt) {
                    pu[mt][0] = pk2(pr[mt][0] * rs, pr[mt][1] * rs);
                    pu[mt][1] = pk2(pr[mt][2] * rs, pr[mt][3] * rs);
                }
                // P-exchange (R4-verified): bpA[c]=P[s][t=8g..+7], bpB[c]=+32
                unsigned A00 = (unsigned)__shfl((int)pu[0][0], src0), A01 = (unsigned)__shfl((int)pu[0][1], src0);
                unsigned A02 = (unsigned)__shfl((int)pu[0][0], src1), A03 = (unsigned)__shfl((int)pu[0][1], src1);
                unsigned B00 = (unsigned)__shfl((int)pu[1][0], src0), B01 = (unsigned)__shfl((int)pu[1][1], src0);
                unsigned B02 = (unsigned)__shfl((int)pu[1][0], src1), B03 = (unsigned)__shfl((int)pu[1][1], src1);
                unsigned C00 = (unsigned)__shfl((int)pu[2][0], src0), C01 = (unsigned)__shfl((int)pu[2][1], src0);
                unsigned C02 = (unsigned)__shfl((int)pu[2][0], src1), C03 = (unsigned)__shfl((int)pu[2][1], src1);
                unsigned D00 = (unsigned)__shfl((int)pu[3][0], src0), D01 = (unsigned)__shfl((int)pu[3][1], src0);
                unsigned D02 = (unsigned)__shfl((int)pu[3][0], src1), D03 = (unsigned)__shfl((int)pu[3][1], src1);
                uint4 q0, q1;
                q0.x = hi ? B00 : A00; q0.y = hi ? B01 : A01; q0.z = hi ? B02 : A02; q0.w = hi ? B03 : A03;
                q1.x = hi ? D00 : C00; q1.y = hi ? D01 : C01; q1.z = hi ? D02 : C02; q1.w = hi ? D03 : C03;
                __builtin_memcpy(&bpA[c], &q0, 16);
                __builtin_memcpy(&bpB[c], &q1, 16);
            }

            // ---- phase 2: per h-block (3 h-tiles): v-GEMM + exchange + PV all c ----
            #pragma unroll 1
            for (int hb = 0; hb < 4; ++hb) {
                unsigned vpk[4][3][2];
                #pragma unroll
                for (int st = 0; st < 4; ++st) {
                    int rr = 16 * st + r; rr = (rr > 54) ? 54 : rr;
                    const float* rowp = xb + (size_t)(oth + rr) * EMB;
                    bf16x8 axm[4];
                    #pragma unroll
                    for (int kk = 0; kk < 3; ++kk) axm[kk] = ldfrag(rowp, 32 * kk + 8 * g);
                    axm[3] = zz;
                    if (g == 0) axm[3] = ldfrag_tail(rowp);
                    #pragma unroll
                    for (int mi = 0; mi < 3; ++mi) {
                        const short* wvp = WvT + (16 * (3 * hb + mi) + r) * WES + 8 * g;
                        f32x4 acc = {0.f, 0.f, 0.f, 0.f};
                        #pragma unroll
                        for (int kk = 0; kk < 4; ++kk)
                            acc = __builtin_amdgcn_mfma_f32_16x16x32_bf16(
                                axm[kk], *(const bf16x8*)(wvp + 32 * kk), acc, 0, 0, 0);
                        vpk[st][mi][0] = pk2(acc[0], acc[1]);
                        vpk[st][mi][1] = pk2(acc[2], acc[3]);
                    }
                }
                // v-exchange (verified) -> va[3][2]
                bf16x8 va[3][2];
                #pragma unroll
                for (int mi = 0; mi < 3; ++mi) {
                    unsigned e00 = (unsigned)__shfl((int)vpk[0][mi][0], src0), e01 = (unsigned)__shfl((int)vpk[0][mi][1], src0);
                    unsigned e02 = (unsigned)__shfl((int)vpk[0][mi][0], src1), e03 = (unsigned)__shfl((int)vpk[0][mi][1], src1);
                    unsigned f00 = (unsigned)__shfl((int)vpk[1][mi][0], src0), f01 = (unsigned)__shfl((int)vpk[1][mi][1], src0);
                    unsigned f02 = (unsigned)__shfl((int)vpk[1][mi][0], src1), f03 = (unsigned)__shfl((int)vpk[1][mi][1], src1);
                    uint4 u0;
                    u0.x = hi ? f00 : e00; u0.y = hi ? f01 : e01; u0.z = hi ? f02 : e02; u0.w = hi ? f03 : e03;
                    unsigned e10 = (unsigned)__shfl((int)vpk[2][mi][0], src0), e11 = (unsigned)__shfl((int)vpk[2][mi][1], src0);
                    unsigned e12 = (unsigned)__shfl((int)vpk[2][mi][0], src1), e13 = (unsigned)__shfl((int)vpk[2][mi][1], src1);
                    unsigned f10 = (unsigned)__shfl((int)vpk[3][mi][0], src0), f11 = (unsigned)__shfl((int)vpk[3][mi][1], src0);
                    unsigned f12 = (unsigned)__shfl((int)vpk[3][mi][0], src1), f13 = (unsigned)__shfl((int)vpk[3][mi][1], src1);
                    uint4 u1;
                    u1.x = hi ? f10 : e10; u1.y = hi ? f11 : e11; u1.z = hi ? f12 : e12; u1.w = hi ? f13 : e13;
                    __builtin_memcpy(&va[mi][0], &u0, 16);
                    __builtin_memcpy(&va[mi][1], &u1, 16);
                }
                // PV + stores for all c
                #pragma unroll
                for (int c = 0; c < 4; ++c) {
                    const int srow  = 16 * c + r;
                    const bool valid = srow < HALFS;
                    float* orow = ob + (size_t)(own + srow) * HEAD;
                    #pragma unroll
                    for (int mi = 0; mi < 3; ++mi) {
                        f32x4 acc = {0.f, 0.f, 0.f, 0.f};
                        acc = __builtin_amdgcn_mfma_f32_16x16x32_bf16(va[mi][0], bpA[c], acc, 0, 0, 0);
                        acc = __builtin_amdgcn_mfma_f32_16x16x32_bf16(va[mi][1], bpB[c], acc, 0, 0, 0);
                        if (valid) {
                            float4 st4; st4.x = acc[0]; st4.y = acc[1]; st4.z = acc[2]; st4.w = acc[3];
                            *(float4*)(orow + 16 * (3 * hb + mi) + 4 * g) = st4;
                        }
                    }
                }
            }
        }
    }
}

extern "C" void kernel_launch(void* const* d_in, const int* in_sizes, int n_in,
                              void* d_out, int out_size, void* d_ws, size_t ws_size,
                              hipStream_t stream) {
    const float* x  = (const float*)d_in[0];
    const float* Wq = (const float*)d_in[1];
    const float* Wk = (const float*)d_in[2];
    const float* Wv = (const float*)d_in[3];
    short* ws = (short*)d_ws;                       // needs (14336+24576)*2 = 77824 B
    int B = in_sizes[0] / (SEQ * EMB);              // 8192
    int prep_elems = MT_SHORTS + HEAD * WES;
    prep<<<(prep_elems + 255) / 256, 256, 0, stream>>>(Wq, Wk, Wv, ws);
    attn_head<<<2048, 256, 0, stream>>>(x, ws, (float*)d_out, B);
}

// Round 21
// 851.176 us; speedup vs baseline: 1.3346x; 1.3346x over previous
//
#include <hip/hip_runtime.h>
#include <hip/hip_bf16.h>

#define SEQ   110
#define HALFS 55
#define EMB   102
#define HEAD  192

typedef short bf16x8 __attribute__((ext_vector_type(8)));
typedef float f32x4  __attribute__((ext_vector_type(4)));

#define MTS   128               // Mt row stride (shorts)
#define MTROWS 112
#define MT_SHORTS (MTROWS * MTS)   // 14336
#define WES   128               // WvT e-stride

__device__ __forceinline__ short f2bf(float f) {
    unsigned u = __float_as_uint(f);
    unsigned r = u + 0x7fffu + ((u >> 16) & 1u);   // RNE
    return (short)(r >> 16);
}
__device__ __forceinline__ unsigned pk2(float a, float b) {
    return ((unsigned)(unsigned short)f2bf(b) << 16) | (unsigned short)f2bf(a);
}

// ws layout: [ Mt : 112x128 bf16 ][ WvT : 192x128 bf16 ]
// Mt[i][j] = scale * sum_h Wq[j][h] * Wk[i][h]; WvT[h][e] = Wv[e][h]; zero-padded.
__global__ void prep(const float* __restrict__ Wq, const float* __restrict__ Wk,
                     const float* __restrict__ Wv, short* __restrict__ ws) {
    int flat = blockIdx.x * 256 + threadIdx.x;
    if (flat < MT_SHORTS) {
        int i = flat >> 7, j = flat & 127;
        float v = 0.0f;
        if (i < EMB && j < EMB) {
            const float4* q4 = (const float4*)(Wq + j * HEAD);
            const float4* k4 = (const float4*)(Wk + i * HEAD);
            float s = 0.0f;
            #pragma unroll 4
            for (int h4 = 0; h4 < HEAD / 4; ++h4) {
                float4 a = q4[h4], b = k4[h4];
                s += a.x * b.x + a.y * b.y + a.z * b.z + a.w * b.w;
            }
            v = s * 0.07216878364870322f;   // 1/sqrt(192)
        }
        ws[flat] = f2bf(v);
    } else if (flat < MT_SHORTS + HEAD * WES) {
        int idx = flat - MT_SHORTS;
        int h = idx >> 7, e = idx & 127;
        float v = (e < EMB) ? Wv[e * HEAD + h] : 0.0f;
        ws[flat] = f2bf(v);
    }
}

// bf16x8 fragment from a global f32 row at even col e (8B-aligned float2 loads)
__device__ __forceinline__ bf16x8 ldfrag(const float* rowp, int e) {
    const float2* p = (const float2*)(rowp + e);
    float2 a = p[0], b = p[1], c = p[2], d = p[3];
    uint4 q;
    q.x = pk2(a.x, a.y); q.y = pk2(b.x, b.y);
    q.z = pk2(c.x, c.y); q.w = pk2(d.x, d.y);
    bf16x8 rr; __builtin_memcpy(&rr, &q, 16); return rr;
}
// tail frag e=96..103 with e=102,103 zeroed (EMB=102)
__device__ __forceinline__ bf16x8 ldfrag_tail(const float* rowp) {
    const float2* p = (const float2*)(rowp + 96);
    float2 a = p[0], b = p[1], c = p[2];
    uint4 q;
    q.x = pk2(a.x, a.y); q.y = pk2(b.x, b.y);
    q.z = pk2(c.x, c.y); q.w = 0u;
    bf16x8 rr; __builtin_memcpy(&rr, &q, 16); return rr;
}

// ZERO-BARRIER / ZERO-LDS: one wave = one batch, all-register, x streamed from
// global (L2). R20 spilled because (256,4) capped arch-VGPRs at 64 (rule: min-waves
// 4 -> 64, 2 -> 128, confirmed R12/R20). (256,2) gives the 128-reg budget the
// ~110-reg live set needs. 2048 blocks x 256 threads = 8192 waves, 1 batch each.
__global__ __launch_bounds__(256, 2)
void attn_head(const float* __restrict__ x, const short* __restrict__ ws,
               float* __restrict__ out, int B) {
    const int tid  = threadIdx.x;
    const int w4   = tid >> 6;        // wave in block
    const int lane = tid & 63;
    const int g    = lane >> 4;
    const int r    = lane & 15;

    const short* Mt  = ws;
    const short* WvT = ws + MT_SHORTS;

    bf16x8 zz = {};
    const int src0 = ((g & 1) << 5) + r;
    const int src1 = src0 + 16;
    const bool hi  = (g >> 1) != 0;

    const int p0      = (int)blockIdx.x * 4 + w4;
    const int wstride = (int)gridDim.x * 4;

    #pragma unroll 1
    for (int p = p0; p < B; p += wstride) {
        const float* xb = x + (size_t)p * (SEQ * EMB);
        float* ob = out + (size_t)p * (SEQ * HEAD);

        #pragma unroll 1
        for (int half = 0; half < 2; ++half) {
            const int own = half * HALFS;        // query rows base
            const int oth = HALFS - own;         // key/value rows base

            // ---- phase 1: bp[c] for all 4 query tiles (all-register) ----
            bf16x8 bpA[4], bpB[4];
            #pragma unroll
            for (int c = 0; c < 4; ++c) {
                bf16x8 bx[4];
                {
                    int rr = 16 * c + r; rr = (rr > 54) ? 54 : rr;
                    const float* rowp = xb + (size_t)(own + rr) * EMB;
                    #pragma unroll
                    for (int kk = 0; kk < 3; ++kk) bx[kk] = ldfrag(rowp, 32 * kk + 8 * g);
                    bx[3] = zz;
                    if (g == 0) bx[3] = ldfrag_tail(rowp);
                }
                // y'^T = Mt @ x_c^T (7 tiles, R18-verified register math)
                unsigned vyp[8][2];
                #pragma unroll
                for (int mt = 0; mt < 7; ++mt) {
                    const short* amp = Mt + (16 * mt + r) * MTS + 8 * g;
                    f32x4 acc = {0.f, 0.f, 0.f, 0.f};
                    #pragma unroll
                    for (int kk = 0; kk < 4; ++kk)
                        acc = __builtin_amdgcn_mfma_f32_16x16x32_bf16(
                            *(const bf16x8*)(amp + 32 * kk), bx[kk], acc, 0, 0, 0);
                    vyp[mt][0] = pk2(acc[0], acc[1]);
                    vyp[mt][1] = pk2(acc[2], acc[3]);
                }
                vyp[7][0] = 0u; vyp[7][1] = 0u;
                // y-exchange -> by[kk] = y'[i=32kk+8g..+7][s=16c+r]
                bf16x8 by[4];
                #pragma unroll
                for (int kk = 0; kk < 4; ++kk) {
                    unsigned e0 = (unsigned)__shfl((int)vyp[2 * kk][0],     src0);
                    unsigned e1 = (unsigned)__shfl((int)vyp[2 * kk][1],     src0);
                    unsigned e2 = (unsigned)__shfl((int)vyp[2 * kk][0],     src1);
                    unsigned e3 = (unsigned)__shfl((int)vyp[2 * kk][1],     src1);
                    unsigned f0 = (unsigned)__shfl((int)vyp[2 * kk + 1][0], src0);
                    unsigned f1 = (unsigned)__shfl((int)vyp[2 * kk + 1][1], src0);
                    unsigned f2 = (unsigned)__shfl((int)vyp[2 * kk + 1][0], src1);
                    unsigned f3 = (unsigned)__shfl((int)vyp[2 * kk + 1][1], src1);
                    uint4 q;
                    q.x = hi ? f0 : e0; q.y = hi ? f1 : e1; q.z = hi ? f2 : e2; q.w = hi ? f3 : e3;
                    __builtin_memcpy(&by[kk], &q, 16);
                }
                // scores: A = key rows t = 16mt + r (streamed, clamped)
                float sc[4][4];
                #pragma unroll
                for (int mt = 0; mt < 4; ++mt) {
                    int rr = 16 * mt + r; rr = (rr > 54) ? 54 : rr;
                    const float* rowp = xb + (size_t)(oth + rr) * EMB;
                    bf16x8 axm[4];
                    #pragma unroll
                    for (int kk = 0; kk < 3; ++kk) axm[kk] = ldfrag(rowp, 32 * kk + 8 * g);
                    axm[3] = zz;
                    if (g == 0) axm[3] = ldfrag_tail(rowp);
                    f32x4 acc = {0.f, 0.f, 0.f, 0.f};
                    #pragma unroll
                    for (int kk = 0; kk < 4; ++kk)
                        acc = __builtin_amdgcn_mfma_f32_16x16x32_bf16(axm[kk], by[kk], acc, 0, 0, 0);
                    #pragma unroll
                    for (int j = 0; j < 4; ++j) sc[mt][j] = acc[j];
                }
                #pragma unroll
                for (int j = 0; j < 4; ++j)
                    if (48 + 4 * g + j >= HALFS) sc[3][j] = -1e30f;   // key padding mask

                // softmax over t
                float mx = -1e30f;
                #pragma unroll
                for (int mt = 0; mt < 4; ++mt) {
                    #pragma unroll
                    for (int j = 0; j < 4; ++j) mx = fmaxf(mx, sc[mt][j]);
                }
                mx = fmaxf(mx, __shfl_xor(mx, 16));
                mx = fmaxf(mx, __shfl_xor(mx, 32));
                float pr[4][4];
                float sum = 0.f;
                #pragma unroll
                for (int mt = 0; mt < 4; ++mt) {
                    #pragma unroll
                    for (int j = 0; j < 4; ++j) { pr[mt][j] = __expf(sc[mt][j] - mx); sum += pr[mt][j]; }
                }
                sum += __shfl_xor(sum, 16);
                sum += __shfl_xor(sum, 32);
                float rs = 1.0f / sum;

                unsigned pu[4][2];
                #pragma unroll
                for (int mt = 0; mt < 4; ++mt) {
                    pu[mt][0] = pk2(pr[mt][0] * rs, pr[mt][1] * rs);
                    pu[mt][1] = pk2(pr[mt][2] * rs, pr[mt][3] * rs);
                }
                // P-exchange (R4-verified)
                unsigned A00 = (unsigned)__shfl((int)pu[0][0], src0), A01 = (unsigned)__shfl((int)pu[0][1], src0);
                unsigned A02 = (unsigned)__shfl((int)pu[0][0], src1), A03 = (unsigned)__shfl((int)pu[0][1], src1);
                unsigned B00 = (unsigned)__shfl((int)pu[1][0], src0), B01 = (unsigned)__shfl((int)pu[1][1], src0);
                unsigned B02 = (unsigned)__shfl((int)pu[1][0], src1), B03 = (unsigned)__shfl((int)pu[1][1], src1);
                unsigned C00 = (unsigned)__shfl((int)pu[2][0], src0), C01 = (unsigned)__shfl((int)pu[2][1], src0);
                unsigned C02 = (unsigned)__shfl((int)pu[2][0], src1), C03 = (unsigned)__shfl((int)pu[2][1], src1);
                unsigned D00 = (unsigned)__shfl((int)pu[3][0], src0), D01 = (unsigned)__shfl((int)pu[3][1], src0);
                unsigned D02 = (unsigned)__shfl((int)pu[3][0], src1), D03 = (unsigned)__shfl((int)pu[3][1], src1);
                uint4 q0, q1;
                q0.x = hi ? B00 : A00; q0.y = hi ? B01 : A01; q0.z = hi ? B02 : A02; q0.w = hi ? B03 : A03;
                q1.x = hi ? D00 : C00; q1.y = hi ? D01 : C01; q1.z = hi ? D02 : C02; q1.w = hi ? D03 : C03;
                __builtin_memcpy(&bpA[c], &q0, 16);
                __builtin_memcpy(&bpB[c], &q1, 16);
            }

            // ---- phase 2: per h-block: v-GEMM + exchange + PV all c ----
            #pragma unroll 1
            for (int hb = 0; hb < 4; ++hb) {
                unsigned vpk[4][3][2];
                #pragma unroll
                for (int st = 0; st < 4; ++st) {
                    int rr = 16 * st + r; rr = (rr > 54) ? 54 : rr;
                    const float* rowp = xb + (size_t)(oth + rr) * EMB;
                    bf16x8 axm[4];
                    #pragma unroll
                    for (int kk = 0; kk < 3; ++kk) axm[kk] = ldfrag(rowp, 32 * kk + 8 * g);
                    axm[3] = zz;
                    if (g == 0) axm[3] = ldfrag_tail(rowp);
                    #pragma unroll
                    for (int mi = 0; mi < 3; ++mi) {
                        const short* wvp = WvT + (16 * (3 * hb + mi) + r) * WES + 8 * g;
                        f32x4 acc = {0.f, 0.f, 0.f, 0.f};
                        #pragma unroll
                        for (int kk = 0; kk < 4; ++kk)
                            acc = __builtin_amdgcn_mfma_f32_16x16x32_bf16(
                                axm[kk], *(const bf16x8*)(wvp + 32 * kk), acc, 0, 0, 0);
                        vpk[st][mi][0] = pk2(acc[0], acc[1]);
                        vpk[st][mi][1] = pk2(acc[2], acc[3]);
                    }
                }
                // v-exchange -> va[3][2]
                bf16x8 va[3][2];
                #pragma unroll
                for (int mi = 0; mi < 3; ++mi) {
                    unsigned e00 = (unsigned)__shfl((int)vpk[0][mi][0], src0), e01 = (unsigned)__shfl((int)vpk[0][mi][1], src0);
                    unsigned e02 = (unsigned)__shfl((int)vpk[0][mi][0], src1), e03 = (unsigned)__shfl((int)vpk[0][mi][1], src1);
                    unsigned f00 = (unsigned)__shfl((int)vpk[1][mi][0], src0), f01 = (unsigned)__shfl((int)vpk[1][mi][1], src0);
                    unsigned f02 = (unsigned)__shfl((int)vpk[1][mi][0], src1), f03 = (unsigned)__shfl((int)vpk[1][mi][1], src1);
                    uint4 u0;
                    u0.x = hi ? f00 : e00; u0.y = hi ? f01 : e01; u0.z = hi ? f02 : e02; u0.w = hi ? f03 : e03;
                    unsigned e10 = (unsigned)__shfl((int)vpk[2][mi][0], src0), e11 = (unsigned)__shfl((int)vpk[2][mi][1], src0);
                    unsigned e12 = (unsigned)__shfl((int)vpk[2][mi][0], src1), e13 = (unsigned)__shfl((int)vpk[2][mi][1], src1);
                    unsigned f10 = (unsigned)__shfl((int)vpk[3][mi][0], src0), f11 = (unsigned)__shfl((int)vpk[3][mi][1], src0);
                    unsigned f12 = (unsigned)__shfl((int)vpk[3][mi][0], src1), f13 = (unsigned)__shfl((int)vpk[3][mi][1], src1);
                    uint4 u1;
                    u1.x = hi ? f10 : e10; u1.y = hi ? f11 : e11; u1.z = hi ? f12 : e12; u1.w = hi ? f13 : e13;
                    __builtin_memcpy(&va[mi][0], &u0, 16);
                    __builtin_memcpy(&va[mi][1], &u1, 16);
                }
                // PV + stores for all c
                #pragma unroll
                for (int c = 0; c < 4; ++c) {
                    const int srow  = 16 * c + r;
                    const bool valid = srow < HALFS;
                    float* orow = ob + (size_t)(own + srow) * HEAD;
                    #pragma unroll
                    for (int mi = 0; mi < 3; ++mi) {
                        f32x4 acc = {0.f, 0.f, 0.f, 0.f};
                        acc = __builtin_amdgcn_mfma_f32_16x16x32_bf16(va[mi][0], bpA[c], acc, 0, 0, 0);
                        acc = __builtin_amdgcn_mfma_f32_16x16x32_bf16(va[mi][1], bpB[c], acc, 0, 0, 0);
                        if (valid) {
                            float4 st4; st4.x = acc[0]; st4.y = acc[1]; st4.z = acc[2]; st4.w = acc[3];
                            *(float4*)(orow + 16 * (3 * hb + mi) + 4 * g) = st4;
                        }
                    }
                }
            }
        }
    }
}

extern "C" void kernel_launch(void* const* d_in, const int* in_sizes, int n_in,
                              void* d_out, int out_size, void* d_ws, size_t ws_size,
                              hipStream_t stream) {
    const float* x  = (const float*)d_in[0];
    const float* Wq = (const float*)d_in[1];
    const float* Wk = (const float*)d_in[2];
    const float* Wv = (const float*)d_in[3];
    short* ws = (short*)d_ws;                       // needs (14336+24576)*2 = 77824 B
    int B = in_sizes[0] / (SEQ * EMB);              // 8192
    int prep_elems = MT_SHORTS + HEAD * WES;
    prep<<<(prep_elems + 255) / 256, 256, 0, stream>>>(Wq, Wk, Wv, ws);
    attn_head<<<2048, 256, 0, stream>>>(x, ws, (float*)d_out, B);
}